// Round 6
// baseline (5498.402 us; speedup 1.0000x reference)
//
#include <hip/hip_runtime.h>
#include <hip/hip_bf16.h>

#define B_ 32
#define N_ 320
#define DIM_ 768
#define H_ 12
#define DH_ 64
#define T_ 64
#define S_ 256
#define MATCH_ 64
#define MLP_ 3072

// ---------------- LayerNorm (row = B*N, dim 768) ----------------
__global__ __launch_bounds__(256) void ln_kernel(
    const float* __restrict__ x, const float* __restrict__ w,
    const float* __restrict__ bb, float* __restrict__ y)
{
  const int row = blockIdx.x;
  const float* xr = x + (size_t)row * DIM_;
  const int t = threadIdx.x;
  float v[3]; float s = 0.f, ss = 0.f;
#pragma unroll
  for (int e = 0; e < 3; ++e) { float u = xr[t + e * 256]; v[e] = u; s += u; ss += u * u; }
#pragma unroll
  for (int off = 32; off >= 1; off >>= 1) { s += __shfl_down(s, off); ss += __shfl_down(ss, off); }
  __shared__ float sh[10];
  const int wid = t >> 6, lane = t & 63;
  if (lane == 0) { sh[wid] = s; sh[4 + wid] = ss; }
  __syncthreads();
  if (t == 0) {
    float S2 = sh[0] + sh[1] + sh[2] + sh[3], SS = sh[4] + sh[5] + sh[6] + sh[7];
    float mu = S2 * (1.0f / DIM_);
    float var = SS * (1.0f / DIM_) - mu * mu;
    sh[8] = mu; sh[9] = rsqrtf(var + 1e-5f);
  }
  __syncthreads();
  const float mu = sh[8], rstd = sh[9];
  float* yr = y + (size_t)row * DIM_;
#pragma unroll
  for (int e = 0; e < 3; ++e) { int c = t + e * 256; yr[c] = (v[e] - mu) * rstd * w[c] + bb[c]; }
}

// ---------------- Generic NT GEMM: C = act(A @ W^T + bias) [+ res] ----------------
// A: M x K row-major, W: O x K row-major, C/res: M x O row-major.
// 128x128 tile, Kstep 16, 256 thr, 8x8/thr (split 4+4 rows/cols, 64 apart).
// M % 128 == 0, O % 128 == 0, K % 16 == 0 required.
template<int ACT, bool HAS_BIAS, bool HAS_RES>
__global__ __launch_bounds__(256) void gemm_nt(
    const float* __restrict__ A, const float* __restrict__ W,
    const float* __restrict__ bias, const float* __restrict__ res,
    float* __restrict__ C, int M, int O, int K)
{
  __shared__ __align__(16) float As[16][132];
  __shared__ __align__(16) float Ws[16][132];
  const int t = threadIdx.x;
  const int tx = t & 15, ty = t >> 4;
  const int m0 = blockIdx.y * 128, o0 = blockIdx.x * 128;
  const int r0 = t >> 2;          // staging row 0..63 (lo half); +64 for hi half
  const int q0 = (t & 3) * 4;     // staging k-offset 0/4/8/12
  const float* ApL = A + (size_t)(m0 + r0) * K + q0;
  const float* ApH = A + (size_t)(m0 + 64 + r0) * K + q0;
  const float* WpL = W + (size_t)(o0 + r0) * K + q0;
  const float* WpH = W + (size_t)(o0 + 64 + r0) * K + q0;
  float acc[8][8] = {};
  for (int k0 = 0; k0 < K; k0 += 16) {
    float4 a0 = *reinterpret_cast<const float4*>(ApL + k0);
    float4 a1 = *reinterpret_cast<const float4*>(ApH + k0);
    float4 w0 = *reinterpret_cast<const float4*>(WpL + k0);
    float4 w1 = *reinterpret_cast<const float4*>(WpH + k0);
    __syncthreads();  // previous iteration's reads complete before overwrite
    As[q0 + 0][r0] = a0.x; As[q0 + 1][r0] = a0.y; As[q0 + 2][r0] = a0.z; As[q0 + 3][r0] = a0.w;
    As[q0 + 0][64 + r0] = a1.x; As[q0 + 1][64 + r0] = a1.y; As[q0 + 2][64 + r0] = a1.z; As[q0 + 3][64 + r0] = a1.w;
    Ws[q0 + 0][r0] = w0.x; Ws[q0 + 1][r0] = w0.y; Ws[q0 + 2][r0] = w0.z; Ws[q0 + 3][r0] = w0.w;
    Ws[q0 + 0][64 + r0] = w1.x; Ws[q0 + 1][64 + r0] = w1.y; Ws[q0 + 2][64 + r0] = w1.z; Ws[q0 + 3][64 + r0] = w1.w;
    __syncthreads();
#pragma unroll
    for (int k = 0; k < 16; ++k) {
      float a[8], b[8];
      *reinterpret_cast<float4*>(&a[0]) = *reinterpret_cast<const float4*>(&As[k][ty * 4]);
      *reinterpret_cast<float4*>(&a[4]) = *reinterpret_cast<const float4*>(&As[k][64 + ty * 4]);
      *reinterpret_cast<float4*>(&b[0]) = *reinterpret_cast<const float4*>(&Ws[k][tx * 4]);
      *reinterpret_cast<float4*>(&b[4]) = *reinterpret_cast<const float4*>(&Ws[k][64 + tx * 4]);
#pragma unroll
      for (int i = 0; i < 8; ++i)
#pragma unroll
        for (int j = 0; j < 8; ++j)
          acc[i][j] = fmaf(a[i], b[j], acc[i][j]);
    }
  }
#pragma unroll
  for (int ih = 0; ih < 2; ++ih) {
#pragma unroll
    for (int i = 0; i < 4; ++i) {
      const size_t m = (size_t)m0 + ih * 64 + ty * 4 + i;
#pragma unroll
      for (int jh = 0; jh < 2; ++jh) {
        const int o = o0 + jh * 64 + tx * 4;
        float4 v;
        v.x = acc[ih * 4 + i][jh * 4 + 0];
        v.y = acc[ih * 4 + i][jh * 4 + 1];
        v.z = acc[ih * 4 + i][jh * 4 + 2];
        v.w = acc[ih * 4 + i][jh * 4 + 3];
        if (HAS_BIAS) {
          float4 bv = *reinterpret_cast<const float4*>(bias + o);
          v.x += bv.x; v.y += bv.y; v.z += bv.z; v.w += bv.w;
        }
        if (ACT == 1) {
          v.x = 0.5f * v.x * (1.0f + erff(v.x * 0.70710678118654752f));
          v.y = 0.5f * v.y * (1.0f + erff(v.y * 0.70710678118654752f));
          v.z = 0.5f * v.z * (1.0f + erff(v.z * 0.70710678118654752f));
          v.w = 0.5f * v.w * (1.0f + erff(v.w * 0.70710678118654752f));
        }
        if (HAS_RES) {
          float4 rv = *reinterpret_cast<const float4*>(res + m * O + o);
          v.x += rv.x; v.y += rv.y; v.z += rv.z; v.w += rv.w;
        }
        *reinterpret_cast<float4*>(C + m * O + o) = v;
      }
    }
  }
}

// ---------------- Batched NT GEMM, K=64: C = scale * A @ B^T (opt mask) ----------------
// batch z: b = z/nh, h = z%nh; operand ptr = base + b*SB + h*SH, row stride RS.
__global__ __launch_bounds__(256) void gemm_bnt64(
    const float* __restrict__ A, long long aSB, long long aSH, int aRS,
    const float* __restrict__ Bm, long long bSB, long long bSH, int bRS,
    float* __restrict__ C, long long cSB, long long cSH, int cRS,
    int nh, float scale, const unsigned char* __restrict__ mask, int maskN)
{
  __shared__ float As[64][65];
  __shared__ float Bs[64][65];
  const int bz = blockIdx.z;
  const int b = bz / nh, h = bz % nh;
  const float* Ab = A + (size_t)b * aSB + (size_t)h * aSH + (size_t)blockIdx.y * 64 * aRS;
  const float* Bb = Bm + (size_t)b * bSB + (size_t)h * bSH + (size_t)blockIdx.x * 64 * bRS;
  const int t = threadIdx.x;
#pragma unroll
  for (int l = 0; l < 4; ++l) {
    int idx = l * 256 + t;
    int r = idx >> 4, q = (idx & 15) * 4;
    float4 av = *reinterpret_cast<const float4*>(Ab + (size_t)r * aRS + q);
    float4 bv = *reinterpret_cast<const float4*>(Bb + (size_t)r * bRS + q);
    As[r][q + 0] = av.x; As[r][q + 1] = av.y; As[r][q + 2] = av.z; As[r][q + 3] = av.w;
    Bs[r][q + 0] = bv.x; Bs[r][q + 1] = bv.y; Bs[r][q + 2] = bv.z; Bs[r][q + 3] = bv.w;
  }
  __syncthreads();
  const int tx = t & 15, ty = t >> 4;
  float acc[4][4] = {};
#pragma unroll 8
  for (int k = 0; k < 64; ++k) {
    float a[4], bq[4];
#pragma unroll
    for (int i = 0; i < 4; ++i) a[i] = As[ty * 4 + i][k];
#pragma unroll
    for (int j = 0; j < 4; ++j) bq[j] = Bs[tx * 4 + j][k];
#pragma unroll
    for (int i = 0; i < 4; ++i)
#pragma unroll
      for (int j = 0; j < 4; ++j)
        acc[i][j] = fmaf(a[i], bq[j], acc[i][j]);
  }
  float* Cb = C + (size_t)b * cSB + (size_t)h * cSH;
  const int i0 = blockIdx.y * 64, j0 = blockIdx.x * 64;
#pragma unroll
  for (int i = 0; i < 4; ++i) {
#pragma unroll
    for (int j = 0; j < 4; ++j) {
      int jj = j0 + tx * 4 + j;
      float vv = acc[i][j] * scale;
      if (mask && mask[(size_t)b * maskN + jj]) vv = -1e9f;
      Cb[(size_t)(i0 + ty * 4 + i) * cRS + jj] = vv;
    }
  }
}

// ---------------- Batched NN GEMM, out width 64: C[m][j] = sum_k A[m][k] B[k][j] ----------------
__global__ __launch_bounds__(256) void gemm_bnn64(
    const float* __restrict__ A, long long aSB, long long aSH, int aRS,
    const float* __restrict__ Bm, long long bSB, long long bSH, int bRS,
    float* __restrict__ C, long long cSB, long long cSH, int cRS,
    int nh, int K)
{
  __shared__ float As[64][17];
  __shared__ float Bs[16][65];
  const int bz = blockIdx.z;
  const int b = bz / nh, h = bz % nh;
  const float* Ab = A + (size_t)b * aSB + (size_t)h * aSH + (size_t)blockIdx.x * 64 * aRS;
  const float* Bb = Bm + (size_t)b * bSB + (size_t)h * bSH;
  const int t = threadIdx.x;
  const int tx = t & 15, ty = t >> 4;
  const int lr = t >> 2, lq = (t & 3) * 4;
  const int br = t >> 4, bq4 = (t & 15) * 4;
  float acc[4][4] = {};
  for (int k0 = 0; k0 < K; k0 += 16) {
    float4 av = *reinterpret_cast<const float4*>(Ab + (size_t)lr * aRS + k0 + lq);
    float4 bv = *reinterpret_cast<const float4*>(Bb + (size_t)(k0 + br) * bRS + bq4);
    As[lr][lq + 0] = av.x; As[lr][lq + 1] = av.y; As[lr][lq + 2] = av.z; As[lr][lq + 3] = av.w;
    Bs[br][bq4 + 0] = bv.x; Bs[br][bq4 + 1] = bv.y; Bs[br][bq4 + 2] = bv.z; Bs[br][bq4 + 3] = bv.w;
    __syncthreads();
#pragma unroll
    for (int k = 0; k < 16; ++k) {
      float a[4], bq[4];
#pragma unroll
      for (int i = 0; i < 4; ++i) a[i] = As[ty * 4 + i][k];
#pragma unroll
      for (int j = 0; j < 4; ++j) bq[j] = Bs[k][tx * 4 + j];
#pragma unroll
      for (int i = 0; i < 4; ++i)
#pragma unroll
        for (int j = 0; j < 4; ++j)
          acc[i][j] = fmaf(a[i], bq[j], acc[i][j]);
    }
    __syncthreads();
  }
  float* Cb = C + (size_t)b * cSB + (size_t)h * cSH + (size_t)blockIdx.x * 64 * cRS;
#pragma unroll
  for (int i = 0; i < 4; ++i)
#pragma unroll
    for (int j = 0; j < 4; ++j)
      Cb[(size_t)(ty * 4 + i) * cRS + tx * 4 + j] = acc[i][j];
}

// ---------------- st_q / st_k GEMM with fused pos_emb add + corr row remap ----------------
// Q[m][o<64] = sum_k (corr[bh, T+s, k] + pos[s, k]) * Wst[o][k] + bst[o]; m = bh*S + s
__global__ __launch_bounds__(256) void gemm_stqk(
    const float* __restrict__ corr, const float* __restrict__ pos,
    const float* __restrict__ Wst, const float* __restrict__ bst,
    float* __restrict__ Q)
{
  __shared__ float As[64][17];
  __shared__ float Ws[64][17];
  const int t = threadIdx.x;
  const int tx = t & 15, ty = t >> 4;
  const int lr = t >> 2, lq = (t & 3) * 4;
  const int m0 = blockIdx.x * 64;
  const int m = m0 + lr;
  const int bh = m >> 8, s = m & 255;  // S_ = 256
  const float* arow = corr + ((size_t)bh * N_ + T_ + s) * N_;
  const float* prow = pos + (size_t)s * N_;
  const float* wrow = Wst + (size_t)lr * N_;
  float acc[4][4] = {};
  for (int k0 = 0; k0 < N_; k0 += 16) {
    float4 av = *reinterpret_cast<const float4*>(arow + k0 + lq);
    float4 pv = *reinterpret_cast<const float4*>(prow + k0 + lq);
    float4 wv = *reinterpret_cast<const float4*>(wrow + k0 + lq);
    As[lr][lq + 0] = av.x + pv.x; As[lr][lq + 1] = av.y + pv.y;
    As[lr][lq + 2] = av.z + pv.z; As[lr][lq + 3] = av.w + pv.w;
    Ws[lr][lq + 0] = wv.x; Ws[lr][lq + 1] = wv.y; Ws[lr][lq + 2] = wv.z; Ws[lr][lq + 3] = wv.w;
    __syncthreads();
#pragma unroll
    for (int k = 0; k < 16; ++k) {
      float a[4], bq[4];
#pragma unroll
      for (int i = 0; i < 4; ++i) a[i] = As[ty * 4 + i][k];
#pragma unroll
      for (int j = 0; j < 4; ++j) bq[j] = Ws[tx * 4 + j][k];
#pragma unroll
      for (int i = 0; i < 4; ++i)
#pragma unroll
        for (int j = 0; j < 4; ++j)
          acc[i][j] = fmaf(a[i], bq[j], acc[i][j]);
    }
    __syncthreads();
  }
#pragma unroll
  for (int i = 0; i < 4; ++i)
#pragma unroll
    for (int j = 0; j < 4; ++j)
      Q[(size_t)(m0 + ty * 4 + i) * 64 + tx * 4 + j] = acc[i][j] + bst[tx * 4 + j];
}

// ---------------- softmax over rows of 256 (in-place) ----------------
__global__ __launch_bounds__(256) void softmax256(float* __restrict__ a)
{
  float* ar = a + (size_t)blockIdx.x * 256;
  const int t = threadIdx.x;
  float v = ar[t];
  float m = v;
#pragma unroll
  for (int off = 32; off >= 1; off >>= 1) m = fmaxf(m, __shfl_xor(m, off));
  __shared__ float sh[6];
  const int wid = t >> 6, lane = t & 63;
  if (lane == 0) sh[wid] = m;
  __syncthreads();
  if (t == 0) sh[4] = fmaxf(fmaxf(sh[0], sh[1]), fmaxf(sh[2], sh[3]));
  __syncthreads();
  const float e = expf(v - sh[4]);
  float s = e;
#pragma unroll
  for (int off = 32; off >= 1; off >>= 1) s += __shfl_xor(s, off);
  if (lane == 0) sh[wid] = s;
  __syncthreads();
  if (t == 0) sh[5] = sh[0] + sh[1] + sh[2] + sh[3];
  __syncthreads();
  ar[t] = e / sh[5];
}

// ---------------- fused f-add + softmax over rows of 320 (in-place on corr) ----------------
__global__ __launch_bounds__(320) void softmax_corr(
    float* __restrict__ corr, const float* __restrict__ f)
{
  const size_t r = blockIdx.x;
  const int qi = (int)(r % N_);
  const size_t bh = r / N_;
  float* cr = corr + r * N_;
  const int t = threadIdx.x;
  float v = cr[t];
  if (qi >= T_ && t < T_) v += f[((bh << 8) + (size_t)(qi - T_)) * 64 + t];
  float m = v;
#pragma unroll
  for (int off = 32; off >= 1; off >>= 1) m = fmaxf(m, __shfl_xor(m, off));
  __shared__ float sh[7];
  const int wid = t >> 6, lane = t & 63;
  if (lane == 0) sh[wid] = m;
  __syncthreads();
  if (t == 0) sh[5] = fmaxf(fmaxf(fmaxf(sh[0], sh[1]), fmaxf(sh[2], sh[3])), sh[4]);
  __syncthreads();
  const float e = expf(v - sh[5]);
  float s = e;
#pragma unroll
  for (int off = 32; off >= 1; off >>= 1) s += __shfl_xor(s, off);
  if (lane == 0) sh[wid] = s;
  __syncthreads();
  if (t == 0) sh[6] = sh[0] + sh[1] + sh[2] + sh[3] + sh[4];
  __syncthreads();
  cr[t] = e / sh[6];
}

extern "C" void kernel_launch(void* const* d_in, const int* in_sizes, int n_in,
                              void* d_out, int out_size, void* d_ws, size_t ws_size,
                              hipStream_t stream) {
  const float* x_rgb = (const float*)d_in[0];
  const float* x_tir = (const float*)d_in[1];
  const unsigned char* mask = (const unsigned char*)d_in[2];
  const float* pos = (const float*)d_in[3];
  // d_in[4] = pos_emb_z (unused by reference)
  const float* n1w = (const float*)d_in[5];
  const float* n1b = (const float*)d_in[6];
  const float* qkvw = (const float*)d_in[7];
  const float* projw = (const float*)d_in[8];
  const float* projb = (const float*)d_in[9];
  const float* stqw = (const float*)d_in[10];
  const float* stqb = (const float*)d_in[11];
  const float* stkw = (const float*)d_in[12];
  const float* stkb = (const float*)d_in[13];
  const float* n2w = (const float*)d_in[14];
  const float* n2b = (const float*)d_in[15];
  const float* fc1w = (const float*)d_in[16];
  const float* fc1b = (const float*)d_in[17];
  const float* fc2w = (const float*)d_in[18];
  const float* fc2b = (const float*)d_in[19];

  float* out = (float*)d_out;
  float* outR = out;
  float* outT = out + (size_t)B_ * N_ * DIM_;
  float* corrR = outT + (size_t)B_ * N_ * DIM_;
  float* corrT = corrR + (size_t)B_ * H_ * N_ * N_;

  // fR/fT live in the outR/outT slots of d_out: they are consumed only by
  // softmax_corr, which completes before Phase C writes outR/outT.
  // (fR needs B*H*S*T = 6.29M floats <= outR's 7.86M slot.)
  float* fR = outR;
  float* fT = outT;

  const size_t needed = ((size_t)2 * B_ * N_ * 3 * DIM_ + (size_t)B_ * N_ * DIM_ +
                         (size_t)4 * B_ * H_ * S_ * MATCH_ +
                         (size_t)B_ * H_ * S_ * S_) * sizeof(float);
  if (ws_size < needed) return;  // insufficient scratch; fail loudly via validation

  float* ws = (float*)d_ws;
  float* qkvR = ws;
  float* qkvT = qkvR + (size_t)B_ * N_ * 3 * DIM_;
  float* tmp = qkvT + (size_t)B_ * N_ * 3 * DIM_;
  float* qR = tmp + (size_t)B_ * N_ * DIM_;
  float* kR = qR + (size_t)B_ * H_ * S_ * MATCH_;
  float* qT = kR + (size_t)B_ * H_ * S_ * MATCH_;
  float* kT = qT + (size_t)B_ * H_ * S_ * MATCH_;
  float* aB = kT + (size_t)B_ * H_ * S_ * MATCH_;
  float* hB = qR;  // alias: h (31.5M floats) fits in q/k/aB region (50.3M), dead by Phase C

  const long long qkvSB = (long long)N_ * 3 * DIM_;
  const long long corrSB = (long long)H_ * N_ * N_;
  const long long corrSH = (long long)N_ * N_;
  const long long qkSB = (long long)H_ * S_ * MATCH_;
  const long long qkSH = (long long)S_ * MATCH_;
  const long long aSB = (long long)H_ * S_ * S_;
  const long long aSH = (long long)S_ * S_;
  const long long fSB = (long long)H_ * S_ * T_;
  const long long fSH = (long long)S_ * T_;

  // ---- Phase A: LN1 + QKV + corr per modality ----
  for (int mo = 0; mo < 2; ++mo) {
    const float* x = mo ? x_tir : x_rgb;
    float* qkv = mo ? qkvT : qkvR;
    float* corr = mo ? corrT : corrR;
    ln_kernel<<<B_ * N_, 256, 0, stream>>>(x, n1w, n1b, tmp);
    gemm_nt<0, false, false><<<dim3((3 * DIM_) / 128, (B_ * N_) / 128), 256, 0, stream>>>(
        tmp, qkvw, nullptr, nullptr, qkv, B_ * N_, 3 * DIM_, DIM_);
    gemm_bnt64<<<dim3(N_ / 64, N_ / 64, B_ * H_), 256, 0, stream>>>(
        qkv, qkvSB, 64, 3 * DIM_,
        qkv + DIM_, qkvSB, 64, 3 * DIM_,
        corr, corrSB, corrSH, N_,
        H_, 0.125f, mask, N_);
  }

  // ---- Phase B: st q/k, cross attention a, f ----
  gemm_stqk<<<(B_ * H_ * S_) / 64, 256, 0, stream>>>(corrR, pos, stqw, stqb, qR);
  gemm_stqk<<<(B_ * H_ * S_) / 64, 256, 0, stream>>>(corrR, pos, stkw, stkb, kR);
  gemm_stqk<<<(B_ * H_ * S_) / 64, 256, 0, stream>>>(corrT, pos, stqw, stqb, qT);
  gemm_stqk<<<(B_ * H_ * S_) / 64, 256, 0, stream>>>(corrT, pos, stkw, stkb, kT);

  // a_rt = softmax(q_r @ k_t^T * msc); f_r = a_rt @ st[..., :T]
  gemm_bnt64<<<dim3(S_ / 64, S_ / 64, B_ * H_), 256, 0, stream>>>(
      qR, qkSB, qkSH, MATCH_, kT, qkSB, qkSH, MATCH_,
      aB, aSB, aSH, S_, H_, 0.125f, nullptr, 0);
  softmax256<<<B_ * H_ * S_, 256, 0, stream>>>(aB);
  gemm_bnn64<<<dim3(S_ / 64, 1, B_ * H_), 256, 0, stream>>>(
      aB, aSB, aSH, S_,
      corrT + (size_t)T_ * N_, corrSB, corrSH, N_,
      fR, fSB, fSH, T_, H_, S_);

  // a_tr = softmax(q_t @ k_r^T * msc); f_t = a_tr @ sr[..., :T]
  gemm_bnt64<<<dim3(S_ / 64, S_ / 64, B_ * H_), 256, 0, stream>>>(
      qT, qkSB, qkSH, MATCH_, kR, qkSB, qkSH, MATCH_,
      aB, aSB, aSH, S_, H_, 0.125f, nullptr, 0);
  softmax256<<<B_ * H_ * S_, 256, 0, stream>>>(aB);
  gemm_bnn64<<<dim3(S_ / 64, 1, B_ * H_), 256, 0, stream>>>(
      aB, aSB, aSH, S_,
      corrR + (size_t)T_ * N_, corrSB, corrSH, N_,
      fT, fSB, fSH, T_, H_, S_);

  // ---- fused f-add + corr softmax (in place in d_out) ----
  softmax_corr<<<B_ * H_ * N_, 320, 0, stream>>>(corrR, fR);
  softmax_corr<<<B_ * H_ * N_, 320, 0, stream>>>(corrT, fT);

  // ---- Phase C: block_out per modality (overwrites fR/fT slots, now dead) ----
  for (int mo = 0; mo < 2; ++mo) {
    const float* x = mo ? x_tir : x_rgb;
    const float* qkv = mo ? qkvT : qkvR;
    const float* corr = mo ? corrT : corrR;
    float* outX = mo ? outT : outR;
    // o = attn @ v  -> tmp (B,N,DIM layout)
    gemm_bnn64<<<dim3(N_ / 64, 1, B_ * H_), 256, 0, stream>>>(
        corr, corrSB, corrSH, N_,
        qkv + 2 * DIM_, qkvSB, 64, 3 * DIM_,
        tmp, (long long)N_ * DIM_, 64, DIM_, H_, N_);
    // x2 = x + o @ proj_w^T + proj_b  -> outX
    gemm_nt<0, true, true><<<dim3(DIM_ / 128, (B_ * N_) / 128), 256, 0, stream>>>(
        tmp, projw, projb, x, outX, B_ * N_, DIM_, DIM_);
    // xn2 = LN2(x2) -> tmp
    ln_kernel<<<B_ * N_, 256, 0, stream>>>(outX, n2w, n2b, tmp);
    // h = gelu(xn2 @ fc1^T + b1) -> hB
    gemm_nt<1, true, false><<<dim3(MLP_ / 128, (B_ * N_) / 128), 256, 0, stream>>>(
        tmp, fc1w, fc1b, nullptr, hB, B_ * N_, MLP_, DIM_);
    // out = x2 + h @ fc2^T + b2 (in place on outX)
    gemm_nt<0, true, true><<<dim3(DIM_ / 128, (B_ * N_) / 128), 256, 0, stream>>>(
        hB, fc2w, fc2b, outX, outX, B_ * N_, DIM_, MLP_);
  }
}

// Round 8
// 2566.728 us; speedup vs baseline: 2.1422x; 2.1422x over previous
//
#include <hip/hip_runtime.h>
#include <hip/hip_bf16.h>

#define B_ 32
#define N_ 320
#define DIM_ 768
#define H_ 12
#define DH_ 64
#define T_ 64
#define S_ 256
#define MATCH_ 64
#define MLP_ 3072

typedef __bf16 bf16x8 __attribute__((ext_vector_type(8)));
typedef float f32x4 __attribute__((ext_vector_type(4)));

// ---------------- fp32 -> bf16 convert (weights) ----------------
__global__ __launch_bounds__(256) void cvt_bf16(
    const float* __restrict__ in, __hip_bfloat16* __restrict__ out, int n)
{
  int i = blockIdx.x * 256 + threadIdx.x;
  if (i < n) out[i] = __float2bfloat16(in[i]);
}

// ---------------- LayerNorm (row = B*N, dim 768), bf16 output ----------------
__global__ __launch_bounds__(256) void ln_kernel(
    const float* __restrict__ x, const float* __restrict__ w,
    const float* __restrict__ bb, __hip_bfloat16* __restrict__ y)
{
  const int row = blockIdx.x;
  const float* xr = x + (size_t)row * DIM_;
  const int t = threadIdx.x;
  float v[3]; float s = 0.f, ss = 0.f;
#pragma unroll
  for (int e = 0; e < 3; ++e) { float u = xr[t + e * 256]; v[e] = u; s += u; ss += u * u; }
#pragma unroll
  for (int off = 32; off >= 1; off >>= 1) { s += __shfl_down(s, off); ss += __shfl_down(ss, off); }
  __shared__ float sh[10];
  const int wid = t >> 6, lane = t & 63;
  if (lane == 0) { sh[wid] = s; sh[4 + wid] = ss; }
  __syncthreads();
  if (t == 0) {
    float S2 = sh[0] + sh[1] + sh[2] + sh[3], SS = sh[4] + sh[5] + sh[6] + sh[7];
    float mu = S2 * (1.0f / DIM_);
    float var = SS * (1.0f / DIM_) - mu * mu;
    sh[8] = mu; sh[9] = rsqrtf(var + 1e-5f);
  }
  __syncthreads();
  const float mu = sh[8], rstd = sh[9];
  __hip_bfloat16* yr = y + (size_t)row * DIM_;
#pragma unroll
  for (int e = 0; e < 3; ++e) {
    int c = t + e * 256;
    yr[c] = __float2bfloat16((v[e] - mu) * rstd * w[c] + bb[c]);
  }
}

// ---------------- MFMA NT GEMM: C = act(A @ W^T + bias) [+ res] ----------------
// A: M x K bf16 row-major, W: O x K bf16 row-major, C fp32 (or Cb bf16) M x O.
// 128x128 tile, 4 waves, BK=64, mfma_f32_16x16x32_bf16.
// M%128==0, O%128==0, K%64==0.
template<int ACT, bool HAS_BIAS, bool HAS_RES, bool OBF>
__global__ __launch_bounds__(256) void gemm_mfma(
    const __hip_bfloat16* __restrict__ A, const __hip_bfloat16* __restrict__ W,
    const float* __restrict__ bias, const float* __restrict__ res,
    float* __restrict__ C, __hip_bfloat16* __restrict__ Cb,
    int M, int O, int K)
{
  __shared__ __align__(16) unsigned short Asb[128][72];  // +8 pad: 144B stride, 2-way max
  __shared__ __align__(16) unsigned short Wsb[128][72];
  const int t = threadIdx.x;
  const int m0 = blockIdx.y * 128, o0 = blockIdx.x * 128;
  const int lane = t & 63, w = t >> 6;
  const int wr = (w >> 1) * 64, wc = (w & 1) * 64;  // wave sub-tile origin
  const int sr = t >> 1;            // staging row 0..127
  const int sk = (t & 1) * 32;      // staging k-half
  const __hip_bfloat16* Ag = A + (size_t)(m0 + sr) * K + sk;
  const __hip_bfloat16* Wg = W + (size_t)(o0 + sr) * K + sk;
  const int fr = lane & 15;         // fragment row/col within 16
  const int kb = (lane >> 4) * 8;   // k base within 32
  f32x4 acc[4][4] = {};
  for (int k0 = 0; k0 < K; k0 += 64) {
    __syncthreads();
#pragma unroll
    for (int j = 0; j < 4; ++j) {
      *reinterpret_cast<bf16x8*>(&Asb[sr][sk + j * 8]) =
          *reinterpret_cast<const bf16x8*>(Ag + k0 + j * 8);
      *reinterpret_cast<bf16x8*>(&Wsb[sr][sk + j * 8]) =
          *reinterpret_cast<const bf16x8*>(Wg + k0 + j * 8);
    }
    __syncthreads();
#pragma unroll
    for (int kc = 0; kc < 2; ++kc) {
      bf16x8 af[4], bfr[4];
#pragma unroll
      for (int i = 0; i < 4; ++i)
        af[i] = *reinterpret_cast<const bf16x8*>(&Asb[wr + i * 16 + fr][kc * 32 + kb]);
#pragma unroll
      for (int j = 0; j < 4; ++j)
        bfr[j] = *reinterpret_cast<const bf16x8*>(&Wsb[wc + j * 16 + fr][kc * 32 + kb]);
#pragma unroll
      for (int i = 0; i < 4; ++i)
#pragma unroll
        for (int j = 0; j < 4; ++j)
          acc[i][j] = __builtin_amdgcn_mfma_f32_16x16x32_bf16(af[i], bfr[j], acc[i][j], 0, 0, 0);
    }
  }
  const int rq = (lane >> 4) * 4;  // C/D: row = 4*(lane>>4)+reg, col = lane&15
#pragma unroll
  for (int i = 0; i < 4; ++i) {
#pragma unroll
    for (int j = 0; j < 4; ++j) {
      const int col = o0 + wc + j * 16 + fr;
      const float bv = HAS_BIAS ? bias[col] : 0.f;
#pragma unroll
      for (int r = 0; r < 4; ++r) {
        const size_t row = (size_t)m0 + wr + i * 16 + rq + r;
        float v = acc[i][j][r] + bv;
        if (ACT == 1) v = 0.5f * v * (1.0f + erff(v * 0.70710678118654752f));
        if (HAS_RES) v += res[row * O + col];
        if (OBF) Cb[row * O + col] = __float2bfloat16(v);
        else     C[row * O + col] = v;
      }
    }
  }
}

// ---------------- Batched NT GEMM, K=64 (fp32): C = scale * A @ B^T (opt mask) ----------------
__global__ __launch_bounds__(256) void gemm_bnt64(
    const float* __restrict__ A, long long aSB, long long aSH, int aRS,
    const float* __restrict__ Bm, long long bSB, long long bSH, int bRS,
    float* __restrict__ C, long long cSB, long long cSH, int cRS,
    int nh, float scale, const unsigned char* __restrict__ mask, int maskN)
{
  __shared__ float As[64][65];
  __shared__ float Bs[64][65];
  const int bz = blockIdx.z;
  const int b = bz / nh, h = bz % nh;
  const float* Ab = A + (size_t)b * aSB + (size_t)h * aSH + (size_t)blockIdx.y * 64 * aRS;
  const float* Bb = Bm + (size_t)b * bSB + (size_t)h * bSH + (size_t)blockIdx.x * 64 * bRS;
  const int t = threadIdx.x;
#pragma unroll
  for (int l = 0; l < 4; ++l) {
    int idx = l * 256 + t;
    int r = idx >> 4, q = (idx & 15) * 4;
    float4 av = *reinterpret_cast<const float4*>(Ab + (size_t)r * aRS + q);
    float4 bv = *reinterpret_cast<const float4*>(Bb + (size_t)r * bRS + q);
    As[r][q + 0] = av.x; As[r][q + 1] = av.y; As[r][q + 2] = av.z; As[r][q + 3] = av.w;
    Bs[r][q + 0] = bv.x; Bs[r][q + 1] = bv.y; Bs[r][q + 2] = bv.z; Bs[r][q + 3] = bv.w;
  }
  __syncthreads();
  const int tx = t & 15, ty = t >> 4;
  float acc[4][4] = {};
#pragma unroll 8
  for (int k = 0; k < 64; ++k) {
    float a[4], bq[4];
#pragma unroll
    for (int i = 0; i < 4; ++i) a[i] = As[ty * 4 + i][k];
#pragma unroll
    for (int j = 0; j < 4; ++j) bq[j] = Bs[tx * 4 + j][k];
#pragma unroll
    for (int i = 0; i < 4; ++i)
#pragma unroll
      for (int j = 0; j < 4; ++j)
        acc[i][j] = fmaf(a[i], bq[j], acc[i][j]);
  }
  float* Cb = C + (size_t)b * cSB + (size_t)h * cSH;
  const int i0 = blockIdx.y * 64, j0 = blockIdx.x * 64;
#pragma unroll
  for (int i = 0; i < 4; ++i) {
#pragma unroll
    for (int j = 0; j < 4; ++j) {
      int jj = j0 + tx * 4 + j;
      float vv = acc[i][j] * scale;
      if (mask && mask[(size_t)b * maskN + jj]) vv = -1e9f;
      Cb[(size_t)(i0 + ty * 4 + i) * cRS + jj] = vv;
    }
  }
}

// ---------------- Batched NN GEMM, out width 64; optional bf16 output ----------------
template<bool OBF>
__global__ __launch_bounds__(256) void gemm_bnn64(
    const float* __restrict__ A, long long aSB, long long aSH, int aRS,
    const float* __restrict__ Bm, long long bSB, long long bSH, int bRS,
    float* __restrict__ C, __hip_bfloat16* __restrict__ Cb16,
    long long cSB, long long cSH, int cRS,
    int nh, int K)
{
  __shared__ float As[64][17];
  __shared__ float Bs[16][65];
  const int bz = blockIdx.z;
  const int b = bz / nh, h = bz % nh;
  const float* Ab = A + (size_t)b * aSB + (size_t)h * aSH + (size_t)blockIdx.x * 64 * aRS;
  const float* Bb = Bm + (size_t)b * bSB + (size_t)h * bSH;
  const int t = threadIdx.x;
  const int tx = t & 15, ty = t >> 4;
  const int lr = t >> 2, lq = (t & 3) * 4;
  const int br = t >> 4, bq4 = (t & 15) * 4;
  float acc[4][4] = {};
  for (int k0 = 0; k0 < K; k0 += 16) {
    float4 av = *reinterpret_cast<const float4*>(Ab + (size_t)lr * aRS + k0 + lq);
    float4 bv = *reinterpret_cast<const float4*>(Bb + (size_t)(k0 + br) * bRS + bq4);
    As[lr][lq + 0] = av.x; As[lr][lq + 1] = av.y; As[lr][lq + 2] = av.z; As[lr][lq + 3] = av.w;
    Bs[br][bq4 + 0] = bv.x; Bs[br][bq4 + 1] = bv.y; Bs[br][bq4 + 2] = bv.z; Bs[br][bq4 + 3] = bv.w;
    __syncthreads();
#pragma unroll
    for (int k = 0; k < 16; ++k) {
      float a[4], bq[4];
#pragma unroll
      for (int i = 0; i < 4; ++i) a[i] = As[ty * 4 + i][k];
#pragma unroll
      for (int j = 0; j < 4; ++j) bq[j] = Bs[k][tx * 4 + j];
#pragma unroll
      for (int i = 0; i < 4; ++i)
#pragma unroll
        for (int j = 0; j < 4; ++j)
          acc[i][j] = fmaf(a[i], bq[j], acc[i][j]);
    }
    __syncthreads();
  }
  const size_t cb = (size_t)b * cSB + (size_t)h * cSH + (size_t)blockIdx.x * 64 * cRS;
#pragma unroll
  for (int i = 0; i < 4; ++i)
#pragma unroll
    for (int j = 0; j < 4; ++j) {
      const size_t off = cb + (size_t)(ty * 4 + i) * cRS + tx * 4 + j;
      if (OBF) Cb16[off] = __float2bfloat16(acc[i][j]);
      else     C[off] = acc[i][j];
    }
}

// ---------------- st_q / st_k GEMM with fused pos_emb add + corr row remap ----------------
__global__ __launch_bounds__(256) void gemm_stqk(
    const float* __restrict__ corr, const float* __restrict__ pos,
    const float* __restrict__ Wst, const float* __restrict__ bst,
    float* __restrict__ Q)
{
  __shared__ float As[64][17];
  __shared__ float Ws[64][17];
  const int t = threadIdx.x;
  const int tx = t & 15, ty = t >> 4;
  const int lr = t >> 2, lq = (t & 3) * 4;
  const int m0 = blockIdx.x * 64;
  const int m = m0 + lr;
  const int bh = m >> 8, s = m & 255;  // S_ = 256
  const float* arow = corr + ((size_t)bh * N_ + T_ + s) * N_;
  const float* prow = pos + (size_t)s * N_;
  const float* wrow = Wst + (size_t)lr * N_;
  float acc[4][4] = {};
  for (int k0 = 0; k0 < N_; k0 += 16) {
    float4 av = *reinterpret_cast<const float4*>(arow + k0 + lq);
    float4 pv = *reinterpret_cast<const float4*>(prow + k0 + lq);
    float4 wv = *reinterpret_cast<const float4*>(wrow + k0 + lq);
    As[lr][lq + 0] = av.x + pv.x; As[lr][lq + 1] = av.y + pv.y;
    As[lr][lq + 2] = av.z + pv.z; As[lr][lq + 3] = av.w + pv.w;
    Ws[lr][lq + 0] = wv.x; Ws[lr][lq + 1] = wv.y; Ws[lr][lq + 2] = wv.z; Ws[lr][lq + 3] = wv.w;
    __syncthreads();
#pragma unroll
    for (int k = 0; k < 16; ++k) {
      float a[4], bq[4];
#pragma unroll
      for (int i = 0; i < 4; ++i) a[i] = As[ty * 4 + i][k];
#pragma unroll
      for (int j = 0; j < 4; ++j) bq[j] = Ws[tx * 4 + j][k];
#pragma unroll
      for (int i = 0; i < 4; ++i)
#pragma unroll
        for (int j = 0; j < 4; ++j)
          acc[i][j] = fmaf(a[i], bq[j], acc[i][j]);
    }
    __syncthreads();
  }
#pragma unroll
  for (int i = 0; i < 4; ++i)
#pragma unroll
    for (int j = 0; j < 4; ++j)
      Q[(size_t)(m0 + ty * 4 + i) * 64 + tx * 4 + j] = acc[i][j] + bst[tx * 4 + j];
}

// ---------------- softmax over rows of 256 (in-place) ----------------
__global__ __launch_bounds__(256) void softmax256(float* __restrict__ a)
{
  float* ar = a + (size_t)blockIdx.x * 256;
  const int t = threadIdx.x;
  float v = ar[t];
  float m = v;
#pragma unroll
  for (int off = 32; off >= 1; off >>= 1) m = fmaxf(m, __shfl_xor(m, off));
  __shared__ float sh[6];
  const int wid = t >> 6, lane = t & 63;
  if (lane == 0) sh[wid] = m;
  __syncthreads();
  if (t == 0) sh[4] = fmaxf(fmaxf(sh[0], sh[1]), fmaxf(sh[2], sh[3]));
  __syncthreads();
  const float e = expf(v - sh[4]);
  float s = e;
#pragma unroll
  for (int off = 32; off >= 1; off >>= 1) s += __shfl_xor(s, off);
  if (lane == 0) sh[wid] = s;
  __syncthreads();
  if (t == 0) sh[5] = sh[0] + sh[1] + sh[2] + sh[3];
  __syncthreads();
  ar[t] = e / sh[5];
}

// ---------------- fused f-add + softmax over rows of 320 (in-place on corr) ----------------
__global__ __launch_bounds__(320) void softmax_corr(
    float* __restrict__ corr, const float* __restrict__ f)
{
  const size_t r = blockIdx.x;
  const int qi = (int)(r % N_);
  const size_t bh = r / N_;
  float* cr = corr + r * N_;
  const int t = threadIdx.x;
  float v = cr[t];
  if (qi >= T_ && t < T_) v += f[((bh << 8) + (size_t)(qi - T_)) * 64 + t];
  float m = v;
#pragma unroll
  for (int off = 32; off >= 1; off >>= 1) m = fmaxf(m, __shfl_xor(m, off));
  __shared__ float sh[7];
  const int wid = t >> 6, lane = t & 63;
  if (lane == 0) sh[wid] = m;
  __syncthreads();
  if (t == 0) sh[5] = fmaxf(fmaxf(fmaxf(sh[0], sh[1]), fmaxf(sh[2], sh[3])), sh[4]);
  __syncthreads();
  const float e = expf(v - sh[5]);
  float s = e;
#pragma unroll
  for (int off = 32; off >= 1; off >>= 1) s += __shfl_xor(s, off);
  if (lane == 0) sh[wid] = s;
  __syncthreads();
  if (t == 0) sh[6] = sh[0] + sh[1] + sh[2] + sh[3] + sh[4];
  __syncthreads();
  cr[t] = e / sh[6];
}

extern "C" void kernel_launch(void* const* d_in, const int* in_sizes, int n_in,
                              void* d_out, int out_size, void* d_ws, size_t ws_size,
                              hipStream_t stream) {
  const float* x_rgb = (const float*)d_in[0];
  const float* x_tir = (const float*)d_in[1];
  const unsigned char* mask = (const unsigned char*)d_in[2];
  const float* pos = (const float*)d_in[3];
  const float* n1w = (const float*)d_in[5];
  const float* n1b = (const float*)d_in[6];
  const float* qkvw = (const float*)d_in[7];
  const float* projw = (const float*)d_in[8];
  const float* projb = (const float*)d_in[9];
  const float* stqw = (const float*)d_in[10];
  const float* stqb = (const float*)d_in[11];
  const float* stkw = (const float*)d_in[12];
  const float* stkb = (const float*)d_in[13];
  const float* n2w = (const float*)d_in[14];
  const float* n2b = (const float*)d_in[15];
  const float* fc1w = (const float*)d_in[16];
  const float* fc1b = (const float*)d_in[17];
  const float* fc2w = (const float*)d_in[18];
  const float* fc2b = (const float*)d_in[19];

  float* out = (float*)d_out;
  float* outR = out;
  float* outT = out + (size_t)B_ * N_ * DIM_;
  float* corrR = outT + (size_t)B_ * N_ * DIM_;
  float* corrT = corrR + (size_t)B_ * H_ * N_ * N_;
  float* fR = outR;  // f lives in out slots; dead before Phase C writes them
  float* fT = outT;

  // ---- workspace layout (float units; bf16 regions reinterpret) ----
  const size_t QKV = (size_t)B_ * N_ * 3 * DIM_;      // 23,592,960
  const size_t QK1 = (size_t)B_ * H_ * S_ * MATCH_;   //  6,291,456
  const size_t ABUF = (size_t)B_ * H_ * S_ * S_;      // 25,165,824
  float* ws = (float*)d_ws;
  float* qkvR = ws;
  float* qkvT = qkvR + QKV;
  float* wB = qkvT + QKV;  // bf16 weights region: 7,077,888 bf16 = 3,538,944 f
  __hip_bfloat16* wqkv = (__hip_bfloat16*)wB;
  __hip_bfloat16* wproj = wqkv + 3 * DIM_ * DIM_;
  __hip_bfloat16* wfc1 = wproj + DIM_ * DIM_;
  __hip_bfloat16* wfc2 = wfc1 + MLP_ * DIM_;
  float* tmpF = wB + 3538944;
  __hip_bfloat16* tmpb = (__hip_bfloat16*)tmpF;        // B*N*DIM bf16 = 3,932,160 f
  float* qR = tmpF + 3932160;
  float* kR = qR + QK1;
  float* qT = kR + QK1;
  float* kT = qT + QK1;
  float* aB = kT + QK1;
  __hip_bfloat16* hb = (__hip_bfloat16*)qR;  // fc1 out: 31.46M bf16 = 15.73M f, q/k/aB dead by then
  const size_t needed = (2 * QKV + 3538944 + 3932160 + 4 * QK1 + ABUF) * sizeof(float);
  if (ws_size < needed) return;

  const long long qkvSB = (long long)N_ * 3 * DIM_;
  const long long corrSB = (long long)H_ * N_ * N_;
  const long long corrSH = (long long)N_ * N_;
  const long long qkSB = (long long)H_ * S_ * MATCH_;
  const long long qkSH = (long long)S_ * MATCH_;
  const long long aSB = (long long)H_ * S_ * S_;
  const long long aSH = (long long)S_ * S_;
  const long long fSB = (long long)H_ * S_ * T_;
  const long long fSH = (long long)S_ * T_;

  // ---- weight conversion (fp32 -> bf16), every launch ----
  cvt_bf16<<<(3 * DIM_ * DIM_ + 255) / 256, 256, 0, stream>>>(qkvw, wqkv, 3 * DIM_ * DIM_);
  cvt_bf16<<<(DIM_ * DIM_ + 255) / 256, 256, 0, stream>>>(projw, wproj, DIM_ * DIM_);
  cvt_bf16<<<(MLP_ * DIM_ + 255) / 256, 256, 0, stream>>>(fc1w, wfc1, MLP_ * DIM_);
  cvt_bf16<<<(MLP_ * DIM_ + 255) / 256, 256, 0, stream>>>(fc2w, wfc2, MLP_ * DIM_);

  // ---- Phase A: LN1 + QKV (MFMA) + corr (fp32) per modality ----
  for (int mo = 0; mo < 2; ++mo) {
    const float* x = mo ? x_tir : x_rgb;
    float* qkv = mo ? qkvT : qkvR;
    float* corr = mo ? corrT : corrR;
    ln_kernel<<<B_ * N_, 256, 0, stream>>>(x, n1w, n1b, tmpb);
    gemm_mfma<0, false, false, false><<<dim3((3 * DIM_) / 128, (B_ * N_) / 128), 256, 0, stream>>>(
        tmpb, wqkv, nullptr, nullptr, qkv, nullptr, B_ * N_, 3 * DIM_, DIM_);
    gemm_bnt64<<<dim3(N_ / 64, N_ / 64, B_ * H_), 256, 0, stream>>>(
        qkv, qkvSB, 64, 3 * DIM_,
        qkv + DIM_, qkvSB, 64, 3 * DIM_,
        corr, corrSB, corrSH, N_,
        H_, 0.125f, mask, N_);
  }

  // ---- Phase B: st q/k, cross attention a, f (all fp32 exact) ----
  gemm_stqk<<<(B_ * H_ * S_) / 64, 256, 0, stream>>>(corrR, pos, stqw, stqb, qR);
  gemm_stqk<<<(B_ * H_ * S_) / 64, 256, 0, stream>>>(corrR, pos, stkw, stkb, kR);
  gemm_stqk<<<(B_ * H_ * S_) / 64, 256, 0, stream>>>(corrT, pos, stqw, stqb, qT);
  gemm_stqk<<<(B_ * H_ * S_) / 64, 256, 0, stream>>>(corrT, pos, stkw, stkb, kT);

  gemm_bnt64<<<dim3(S_ / 64, S_ / 64, B_ * H_), 256, 0, stream>>>(
      qR, qkSB, qkSH, MATCH_, kT, qkSB, qkSH, MATCH_,
      aB, aSB, aSH, S_, H_, 0.125f, nullptr, 0);
  softmax256<<<B_ * H_ * S_, 256, 0, stream>>>(aB);
  gemm_bnn64<false><<<dim3(S_ / 64, 1, B_ * H_), 256, 0, stream>>>(
      aB, aSB, aSH, S_,
      corrT + (size_t)T_ * N_, corrSB, corrSH, N_,
      fR, nullptr, fSB, fSH, T_, H_, S_);

  gemm_bnt64<<<dim3(S_ / 64, S_ / 64, B_ * H_), 256, 0, stream>>>(
      qT, qkSB, qkSH, MATCH_, kR, qkSB, qkSH, MATCH_,
      aB, aSB, aSH, S_, H_, 0.125f, nullptr, 0);
  softmax256<<<B_ * H_ * S_, 256, 0, stream>>>(aB);
  gemm_bnn64<false><<<dim3(S_ / 64, 1, B_ * H_), 256, 0, stream>>>(
      aB, aSB, aSH, S_,
      corrR + (size_t)T_ * N_, corrSB, corrSH, N_,
      fT, nullptr, fSB, fSH, T_, H_, S_);

  // ---- fused f-add + corr softmax (in place in d_out) ----
  softmax_corr<<<B_ * H_ * N_, 320, 0, stream>>>(corrR, fR);
  softmax_corr<<<B_ * H_ * N_, 320, 0, stream>>>(corrT, fT);

  // ---- Phase C: block_out per modality ----
  for (int mo = 0; mo < 2; ++mo) {
    const float* x = mo ? x_tir : x_rgb;
    const float* qkv = mo ? qkvT : qkvR;
    const float* corr = mo ? corrT : corrR;
    float* outX = mo ? outT : outR;
    // o = attn @ v -> tmpb (bf16, proj input)
    gemm_bnn64<true><<<dim3(N_ / 64, 1, B_ * H_), 256, 0, stream>>>(
        corr, corrSB, corrSH, N_,
        qkv + 2 * DIM_, qkvSB, 64, 3 * DIM_,
        nullptr, tmpb, (long long)N_ * DIM_, 64, DIM_, H_, N_);
    // x2 = x + o @ proj_w^T + proj_b -> outX
    gemm_mfma<0, true, true, false><<<dim3(DIM_ / 128, (B_ * N_) / 128), 256, 0, stream>>>(
        tmpb, wproj, projb, x, outX, nullptr, B_ * N_, DIM_, DIM_);
    // xn2 = LN2(x2) -> tmpb (bf16)
    ln_kernel<<<B_ * N_, 256, 0, stream>>>(outX, n2w, n2b, tmpb);
    // h = gelu(xn2 @ fc1^T + b1) -> hb (bf16)
    gemm_mfma<1, true, false, true><<<dim3(MLP_ / 128, (B_ * N_) / 128), 256, 0, stream>>>(
        tmpb, wfc1, fc1b, nullptr, nullptr, hb, B_ * N_, MLP_, DIM_);
    // out = x2 + h @ fc2^T + b2 (in place on outX)
    gemm_mfma<0, true, true, false><<<dim3(DIM_ / 128, (B_ * N_) / 128), 256, 0, stream>>>(
        hb, wfc2, fc2b, outX, outX, nullptr, B_ * N_, DIM_, MLP_);
  }
}

// Round 10
// 1941.452 us; speedup vs baseline: 2.8321x; 1.3221x over previous
//
#include <hip/hip_runtime.h>
#include <hip/hip_bf16.h>

#define B_ 32
#define N_ 320
#define DIM_ 768
#define H_ 12
#define DH_ 64
#define T_ 64
#define S_ 256
#define MATCH_ 64
#define MLP_ 3072

typedef __bf16 bf16x8 __attribute__((ext_vector_type(8)));
typedef float f32x4 __attribute__((ext_vector_type(4)));

__device__ inline bf16x8 cvt8(float4 a, float4 b) {
  union { bf16x8 v; __hip_bfloat16 h8[8]; } r;
  r.h8[0] = __float2bfloat16(a.x); r.h8[1] = __float2bfloat16(a.y);
  r.h8[2] = __float2bfloat16(a.z); r.h8[3] = __float2bfloat16(a.w);
  r.h8[4] = __float2bfloat16(b.x); r.h8[5] = __float2bfloat16(b.y);
  r.h8[6] = __float2bfloat16(b.z); r.h8[7] = __float2bfloat16(b.w);
  return r.v;
}

// ---------------- fp32 -> bf16 convert (weights) ----------------
__global__ __launch_bounds__(256) void cvt_bf16(
    const float* __restrict__ in, __hip_bfloat16* __restrict__ out, int n)
{
  int i = blockIdx.x * 256 + threadIdx.x;
  if (i < n) out[i] = __float2bfloat16(in[i]);
}

// ---------------- stack st_q_w / st_k_w -> wstk bf16 [128][320], bstk f32 [128] ----------------
__global__ __launch_bounds__(256) void cvt_stk(
    const float* __restrict__ qw, const float* __restrict__ qb,
    const float* __restrict__ kw, const float* __restrict__ kb,
    __hip_bfloat16* __restrict__ wstk, float* __restrict__ bstk)
{
  int i = blockIdx.x * 256 + threadIdx.x;
  if (i < 64 * N_) wstk[i] = __float2bfloat16(qw[i]);
  else if (i < 128 * N_) wstk[i] = __float2bfloat16(kw[i - 64 * N_]);
  if (i < 64) bstk[i] = qb[i];
  else if (i >= 64 && i < 128) bstk[i] = kb[i - 64];
}

// ---------------- LayerNorm (row = B*N, dim 768), bf16 output ----------------
__global__ __launch_bounds__(256) void ln_kernel(
    const float* __restrict__ x, const float* __restrict__ w,
    const float* __restrict__ bb, __hip_bfloat16* __restrict__ y)
{
  const int row = blockIdx.x;
  const float* xr = x + (size_t)row * DIM_;
  const int t = threadIdx.x;
  float v[3]; float s = 0.f, ss = 0.f;
#pragma unroll
  for (int e = 0; e < 3; ++e) { float u = xr[t + e * 256]; v[e] = u; s += u; ss += u * u; }
#pragma unroll
  for (int off = 32; off >= 1; off >>= 1) { s += __shfl_down(s, off); ss += __shfl_down(ss, off); }
  __shared__ float sh[10];
  const int wid = t >> 6, lane = t & 63;
  if (lane == 0) { sh[wid] = s; sh[4 + wid] = ss; }
  __syncthreads();
  if (t == 0) {
    float S2 = sh[0] + sh[1] + sh[2] + sh[3], SS = sh[4] + sh[5] + sh[6] + sh[7];
    float mu = S2 * (1.0f / DIM_);
    float var = SS * (1.0f / DIM_) - mu * mu;
    sh[8] = mu; sh[9] = rsqrtf(var + 1e-5f);
  }
  __syncthreads();
  const float mu = sh[8], rstd = sh[9];
  __hip_bfloat16* yr = y + (size_t)row * DIM_;
#pragma unroll
  for (int e = 0; e < 3; ++e) {
    int c = t + e * 256;
    yr[c] = __float2bfloat16((v[e] - mu) * rstd * w[c] + bb[c]);
  }
}

// ---------------- MFMA NT GEMM: C = act(A @ W^T + bias) [+ res] ----------------
// 128x128 tile, 4 waves, BK=64. (validated round 8)
template<int ACT, bool HAS_BIAS, bool HAS_RES, bool OBF>
__global__ __launch_bounds__(256) void gemm_mfma(
    const __hip_bfloat16* __restrict__ A, const __hip_bfloat16* __restrict__ W,
    const float* __restrict__ bias, const float* __restrict__ res,
    float* __restrict__ C, __hip_bfloat16* __restrict__ Cb,
    int M, int O, int K)
{
  __shared__ __align__(16) unsigned short Asb[128][72];
  __shared__ __align__(16) unsigned short Wsb[128][72];
  const int t = threadIdx.x;
  const int m0 = blockIdx.y * 128, o0 = blockIdx.x * 128;
  const int lane = t & 63, w = t >> 6;
  const int wr = (w >> 1) * 64, wc = (w & 1) * 64;
  const int sr = t >> 1;
  const int sk = (t & 1) * 32;
  const __hip_bfloat16* Ag = A + (size_t)(m0 + sr) * K + sk;
  const __hip_bfloat16* Wg = W + (size_t)(o0 + sr) * K + sk;
  const int fr = lane & 15;
  const int kb = (lane >> 4) * 8;
  f32x4 acc[4][4] = {};
  for (int k0 = 0; k0 < K; k0 += 64) {
    __syncthreads();
#pragma unroll
    for (int j = 0; j < 4; ++j) {
      *reinterpret_cast<bf16x8*>(&Asb[sr][sk + j * 8]) =
          *reinterpret_cast<const bf16x8*>(Ag + k0 + j * 8);
      *reinterpret_cast<bf16x8*>(&Wsb[sr][sk + j * 8]) =
          *reinterpret_cast<const bf16x8*>(Wg + k0 + j * 8);
    }
    __syncthreads();
#pragma unroll
    for (int kc = 0; kc < 2; ++kc) {
      bf16x8 af[4], bfr[4];
#pragma unroll
      for (int i = 0; i < 4; ++i)
        af[i] = *reinterpret_cast<const bf16x8*>(&Asb[wr + i * 16 + fr][kc * 32 + kb]);
#pragma unroll
      for (int j = 0; j < 4; ++j)
        bfr[j] = *reinterpret_cast<const bf16x8*>(&Wsb[wc + j * 16 + fr][kc * 32 + kb]);
#pragma unroll
      for (int i = 0; i < 4; ++i)
#pragma unroll
        for (int j = 0; j < 4; ++j)
          acc[i][j] = __builtin_amdgcn_mfma_f32_16x16x32_bf16(af[i], bfr[j], acc[i][j], 0, 0, 0);
    }
  }
  const int rq = (lane >> 4) * 4;
#pragma unroll
  for (int i = 0; i < 4; ++i) {
#pragma unroll
    for (int j = 0; j < 4; ++j) {
      const int col = o0 + wc + j * 16 + fr;
      const float bv = HAS_BIAS ? bias[col] : 0.f;
#pragma unroll
      for (int r = 0; r < 4; ++r) {
        const size_t row = (size_t)m0 + wr + i * 16 + rq + r;
        float v = acc[i][j][r] + bv;
        if (ACT == 1) v = 0.5f * v * (1.0f + erff(v * 0.70710678118654752f));
        if (HAS_RES) v += res[row * O + col];
        if (OBF) Cb[row * O + col] = __float2bfloat16(v);
        else     C[row * O + col] = v;
      }
    }
  }
}

// ---------------- Batched MFMA NT: C[b,h] = scale*(A @ B^T) (opt mask, opt fp32-A cvt) ----------------
// 64x64 tile, 4 waves (wave w: rows w*16..w*16+15, all 64 cols), BK=64 loop.
// A: bf16 (or fp32, converted in staging), B: bf16. Strides in elements.
template<bool AF32, bool OBF, bool MASK>
__global__ __launch_bounds__(256) void bmm_mfma(
    const void* __restrict__ Ap, long long aSB, long long aSH, int aRS,
    const __hip_bfloat16* __restrict__ Bp, long long bSB, long long bSH, int bRS,
    float* __restrict__ C, __hip_bfloat16* __restrict__ Cb,
    long long cSB, long long cSH, int cRS,
    int nh, int K, float scale,
    const unsigned char* __restrict__ mask, int maskN)
{
  __shared__ __align__(16) unsigned short Asb[64][72];
  __shared__ __align__(16) unsigned short Bsb[64][72];
  const int t = threadIdx.x;
  const int b = blockIdx.z / nh, h = blockIdx.z % nh;
  const int i0 = blockIdx.y * 64, j0 = blockIdx.x * 64;
  const int lane = t & 63, w = t >> 6;
  const int sr = t >> 2, sk = (t & 3) * 16;
  const size_t aBase = (size_t)b * aSB + (size_t)h * aSH + (size_t)(i0 + sr) * aRS + sk;
  const __hip_bfloat16* Bg = Bp + (size_t)b * bSB + (size_t)h * bSH + (size_t)(j0 + sr) * bRS + sk;
  const int fr = lane & 15, kb = (lane >> 4) * 8;
  const int wr = w * 16;
  f32x4 acc[4] = {};
  for (int k0 = 0; k0 < K; k0 += 64) {
    __syncthreads();
    if (AF32) {
      const float* Ag = (const float*)Ap + aBase + k0;
#pragma unroll
      for (int u = 0; u < 2; ++u) {
        float4 x0 = *reinterpret_cast<const float4*>(Ag + u * 8);
        float4 x1 = *reinterpret_cast<const float4*>(Ag + u * 8 + 4);
        *reinterpret_cast<bf16x8*>(&Asb[sr][sk + u * 8]) = cvt8(x0, x1);
      }
    } else {
      const __hip_bfloat16* Ag = (const __hip_bfloat16*)Ap + aBase + k0;
      *reinterpret_cast<bf16x8*>(&Asb[sr][sk + 0]) = *reinterpret_cast<const bf16x8*>(Ag);
      *reinterpret_cast<bf16x8*>(&Asb[sr][sk + 8]) = *reinterpret_cast<const bf16x8*>(Ag + 8);
    }
    *reinterpret_cast<bf16x8*>(&Bsb[sr][sk + 0]) = *reinterpret_cast<const bf16x8*>(Bg + k0);
    *reinterpret_cast<bf16x8*>(&Bsb[sr][sk + 8]) = *reinterpret_cast<const bf16x8*>(Bg + k0 + 8);
    __syncthreads();
#pragma unroll
    for (int kc = 0; kc < 2; ++kc) {
      bf16x8 af = *reinterpret_cast<const bf16x8*>(&Asb[wr + fr][kc * 32 + kb]);
#pragma unroll
      for (int j = 0; j < 4; ++j) {
        bf16x8 bf = *reinterpret_cast<const bf16x8*>(&Bsb[j * 16 + fr][kc * 32 + kb]);
        acc[j] = __builtin_amdgcn_mfma_f32_16x16x32_bf16(af, bf, acc[j], 0, 0, 0);
      }
    }
  }
  const int rq = (lane >> 4) * 4;
  const size_t cBase = (size_t)b * cSB + (size_t)h * cSH;
#pragma unroll
  for (int j = 0; j < 4; ++j) {
    const int col = j0 + j * 16 + fr;
    bool msk = false;
    if (MASK) msk = mask[(size_t)b * maskN + col] != 0;
#pragma unroll
    for (int r = 0; r < 4; ++r) {
      const int row = i0 + wr + rq + r;
      float v = acc[j][r] * scale;
      if (MASK && msk) v = -1e9f;
      const size_t off = cBase + (size_t)row * cRS + col;
      if (OBF) Cb[off] = __float2bfloat16(v);
      else     C[off] = v;
    }
  }
}

// ---------------- fused st_q|st_k MFMA: qk[m][0..127] = bf16((corr+pos) @ wstk^T + bstk) ----------------
// 128 rows x 128 cols tile (full O), BK=64, K=320. A converted fp32->bf16 in staging with row remap.
__global__ __launch_bounds__(256) void stqk_mfma(
    const float* __restrict__ corr, const float* __restrict__ pos,
    const __hip_bfloat16* __restrict__ wstk, const float* __restrict__ bstk,
    __hip_bfloat16* __restrict__ qk)
{
  __shared__ __align__(16) unsigned short Asb[128][72];
  __shared__ __align__(16) unsigned short Wsb[128][72];
  const int t = threadIdx.x;
  const int m0 = blockIdx.x * 128;
  const int lane = t & 63, w = t >> 6;
  const int wr = (w >> 1) * 64, wc = (w & 1) * 64;
  const int sr = t >> 1, skh = (t & 1) * 32;
  const int m = m0 + sr, bh = m >> 8, s = m & 255;
  const float* arow = corr + ((size_t)bh * N_ + T_ + s) * N_ + skh;
  const float* prow = pos + (size_t)s * N_ + skh;
  const __hip_bfloat16* Wg = wstk + (size_t)sr * N_ + skh;
  const int fr = lane & 15, kb = (lane >> 4) * 8;
  f32x4 acc[4][4] = {};
  for (int k0 = 0; k0 < N_; k0 += 64) {
    __syncthreads();
#pragma unroll
    for (int u = 0; u < 4; ++u) {
      float4 x0 = *reinterpret_cast<const float4*>(arow + k0 + u * 8);
      float4 x1 = *reinterpret_cast<const float4*>(arow + k0 + u * 8 + 4);
      float4 p0 = *reinterpret_cast<const float4*>(prow + k0 + u * 8);
      float4 p1 = *reinterpret_cast<const float4*>(prow + k0 + u * 8 + 4);
      float4 s0 = make_float4(x0.x + p0.x, x0.y + p0.y, x0.z + p0.z, x0.w + p0.w);
      float4 s1 = make_float4(x1.x + p1.x, x1.y + p1.y, x1.z + p1.z, x1.w + p1.w);
      *reinterpret_cast<bf16x8*>(&Asb[sr][skh + u * 8]) = cvt8(s0, s1);
      *reinterpret_cast<bf16x8*>(&Wsb[sr][skh + u * 8]) =
          *reinterpret_cast<const bf16x8*>(Wg + k0 + u * 8);
    }
    __syncthreads();
#pragma unroll
    for (int kc = 0; kc < 2; ++kc) {
      bf16x8 af[4], bfr[4];
#pragma unroll
      for (int i = 0; i < 4; ++i)
        af[i] = *reinterpret_cast<const bf16x8*>(&Asb[wr + i * 16 + fr][kc * 32 + kb]);
#pragma unroll
      for (int j = 0; j < 4; ++j)
        bfr[j] = *reinterpret_cast<const bf16x8*>(&Wsb[wc + j * 16 + fr][kc * 32 + kb]);
#pragma unroll
      for (int i = 0; i < 4; ++i)
#pragma unroll
        for (int j = 0; j < 4; ++j)
          acc[i][j] = __builtin_amdgcn_mfma_f32_16x16x32_bf16(af[i], bfr[j], acc[i][j], 0, 0, 0);
    }
  }
  const int rq = (lane >> 4) * 4;
#pragma unroll
  for (int i = 0; i < 4; ++i) {
#pragma unroll
    for (int j = 0; j < 4; ++j) {
      const int col = wc + j * 16 + fr;
      const float bv = bstk[col];
#pragma unroll
      for (int r = 0; r < 4; ++r) {
        const size_t row = (size_t)m0 + wr + i * 16 + rq + r;
        qk[row * 128 + col] = __float2bfloat16(acc[i][j][r] + bv);
      }
    }
  }
}

// ---------------- transpose+cvt: stT[bh][c][s] = bf16(corr[bh][T+s][c]), c<64, s<256 ----------------
__global__ __launch_bounds__(256) void transT_kernel(
    const float* __restrict__ corr, __hip_bfloat16* __restrict__ stT)
{
  __shared__ float L[64][65];
  const int t = threadIdx.x;
  const int bh = blockIdx.y, sb = blockIdx.x;  // sb 0..3
  const size_t base = ((size_t)bh * N_ + T_ + (size_t)sb * 64) * N_;
#pragma unroll
  for (int it = 0; it < 4; ++it) {
    int r = it * 16 + (t >> 4);
    int c = (t & 15) * 4;
    float4 v = *reinterpret_cast<const float4*>(corr + base + (size_t)r * N_ + c);
    L[r][c] = v.x; L[r][c + 1] = v.y; L[r][c + 2] = v.z; L[r][c + 3] = v.w;
  }
  __syncthreads();
  const int cr = t >> 2, s0 = (t & 3) * 16;
  union { bf16x8 v; __hip_bfloat16 h8[8]; } o0, o1;
#pragma unroll
  for (int i = 0; i < 8; ++i) o0.h8[i] = __float2bfloat16(L[s0 + i][cr]);
#pragma unroll
  for (int i = 0; i < 8; ++i) o1.h8[i] = __float2bfloat16(L[s0 + 8 + i][cr]);
  __hip_bfloat16* dst = stT + ((size_t)bh * 64 + cr) * 256 + sb * 64 + s0;
  *reinterpret_cast<bf16x8*>(dst) = o0.v;
  *reinterpret_cast<bf16x8*>(dst + 8) = o1.v;
}

// ---------------- transpose: vT[bh][j][n] = qkvb[b][n][2*768 + h*64 + j], j<64, n<320 ----------------
__global__ __launch_bounds__(256) void transV_kernel(
    const __hip_bfloat16* __restrict__ qkvb, __hip_bfloat16* __restrict__ vT)
{
  __shared__ unsigned short L[64][72];
  const int t = threadIdx.x;
  const int bh = blockIdx.y, nb = blockIdx.x;  // nb 0..4
  const int b = bh / H_, h = bh % H_;
  const size_t base = (size_t)b * N_ * 3 * DIM_ + (size_t)(nb * 64) * 3 * DIM_ + 2 * DIM_ + h * 64;
#pragma unroll
  for (int it = 0; it < 4; ++it) {
    int r = it * 16 + (t >> 4);
    int j = (t & 15) * 4;
    *reinterpret_cast<uint2*>(&L[r][j]) =
        *reinterpret_cast<const uint2*>(qkvb + base + (size_t)r * 3 * DIM_ + j);
  }
  __syncthreads();
  const int jr = t >> 2, n0 = (t & 3) * 16;
  union { bf16x8 v; unsigned short u8[8]; } o0, o1;
#pragma unroll
  for (int i = 0; i < 8; ++i) o0.u8[i] = L[n0 + i][jr];
#pragma unroll
  for (int i = 0; i < 8; ++i) o1.u8[i] = L[n0 + 8 + i][jr];
  __hip_bfloat16* dst = vT + ((size_t)bh * 64 + jr) * 320 + nb * 64 + n0;
  *reinterpret_cast<bf16x8*>(dst) = o0.v;
  *reinterpret_cast<bf16x8*>(dst + 8) = o1.v;
}

// ---------------- softmax over rows of 256 (in-place fp32) ----------------
__global__ __launch_bounds__(256) void softmax256(float* __restrict__ a)
{
  float* ar = a + (size_t)blockIdx.x * 256;
  const int t = threadIdx.x;
  float v = ar[t];
  float m = v;
#pragma unroll
  for (int off = 32; off >= 1; off >>= 1) m = fmaxf(m, __shfl_xor(m, off));
  __shared__ float sh[6];
  const int wid = t >> 6, lane = t & 63;
  if (lane == 0) sh[wid] = m;
  __syncthreads();
  if (t == 0) sh[4] = fmaxf(fmaxf(sh[0], sh[1]), fmaxf(sh[2], sh[3]));
  __syncthreads();
  const float e = expf(v - sh[4]);
  float s = e;
#pragma unroll
  for (int off = 32; off >= 1; off >>= 1) s += __shfl_xor(s, off);
  if (lane == 0) sh[wid] = s;
  __syncthreads();
  if (t == 0) sh[5] = sh[0] + sh[1] + sh[2] + sh[3];
  __syncthreads();
  ar[t] = e / sh[5];
}

// ---------------- fused f-add + softmax over rows of 320 (in-place on corr) ----------------
__global__ __launch_bounds__(320) void softmax_corr(
    float* __restrict__ corr, const float* __restrict__ f)
{
  const size_t r = blockIdx.x;
  const int qi = (int)(r % N_);
  const size_t bh = r / N_;
  float* cr = corr + r * N_;
  const int t = threadIdx.x;
  float v = cr[t];
  if (qi >= T_ && t < T_) v += f[((bh << 8) + (size_t)(qi - T_)) * 64 + t];
  float m = v;
#pragma unroll
  for (int off = 32; off >= 1; off >>= 1) m = fmaxf(m, __shfl_xor(m, off));
  __shared__ float sh[7];
  const int wid = t >> 6, lane = t & 63;
  if (lane == 0) sh[wid] = m;
  __syncthreads();
  if (t == 0) sh[5] = fmaxf(fmaxf(fmaxf(sh[0], sh[1]), fmaxf(sh[2], sh[3])), sh[4]);
  __syncthreads();
  const float e = expf(v - sh[5]);
  float s = e;
#pragma unroll
  for (int off = 32; off >= 1; off >>= 1) s += __shfl_xor(s, off);
  if (lane == 0) sh[wid] = s;
  __syncthreads();
  if (t == 0) sh[6] = sh[0] + sh[1] + sh[2] + sh[3] + sh[4];
  __syncthreads();
  cr[t] = e / sh[6];
}

extern "C" void kernel_launch(void* const* d_in, const int* in_sizes, int n_in,
                              void* d_out, int out_size, void* d_ws, size_t ws_size,
                              hipStream_t stream) {
  const float* x_rgb = (const float*)d_in[0];
  const float* x_tir = (const float*)d_in[1];
  const unsigned char* mask = (const unsigned char*)d_in[2];
  const float* pos = (const float*)d_in[3];
  const float* n1w = (const float*)d_in[5];
  const float* n1b = (const float*)d_in[6];
  const float* qkvw = (const float*)d_in[7];
  const float* projw = (const float*)d_in[8];
  const float* projb = (const float*)d_in[9];
  const float* stqw = (const float*)d_in[10];
  const float* stqb = (const float*)d_in[11];
  const float* stkw = (const float*)d_in[12];
  const float* stkb = (const float*)d_in[13];
  const float* n2w = (const float*)d_in[14];
  const float* n2b = (const float*)d_in[15];
  const float* fc1w = (const float*)d_in[16];
  const float* fc1b = (const float*)d_in[17];
  const float* fc2w = (const float*)d_in[18];
  const float* fc2b = (const float*)d_in[19];

  float* out = (float*)d_out;
  float* outR = out;
  float* outT = out + (size_t)B_ * N_ * DIM_;
  float* corrR = outT + (size_t)B_ * N_ * DIM_;
  float* corrT = corrR + (size_t)B_ * H_ * N_ * N_;
  float* fR = outR;  // f in out slots; consumed by softmax_corr before Phase C writes out
  float* fT = outT;

  // ---- workspace layout ----
  __hip_bfloat16* qkvRb = (__hip_bfloat16*)d_ws;                 // 23,592,960 bf16
  __hip_bfloat16* qkvTb = qkvRb + 23592960;                      // 23,592,960
  __hip_bfloat16* wqkv  = qkvTb + 23592960;                      //  1,769,472
  __hip_bfloat16* wproj = wqkv + 1769472;                        //    589,824
  __hip_bfloat16* wfc1  = wproj + 589824;                        //  2,359,296
  __hip_bfloat16* wfc2  = wfc1 + 2359296;                        //  2,359,296
  __hip_bfloat16* wstk  = wfc2 + 2359296;                        //     40,960
  float* bstk = (float*)(wstk + 40960);                          //        128 f
  __hip_bfloat16* tmpb = (__hip_bfloat16*)(bstk + 128);          //  7,864,320 bf16
  __hip_bfloat16* qkR = tmpb + 7864320;                          // 12,582,912
  __hip_bfloat16* qkT = qkR + 12582912;                          // 12,582,912
  __hip_bfloat16* stT = qkT + 12582912;                          //  6,291,456
  __hip_bfloat16* vT  = stT + 6291456;                           //  7,864,320
  float* aB = (float*)(vT + 7864320);                            // 25,165,824 f
  __hip_bfloat16* hb = qkR;  // fc1 out: 31,457,280 bf16 == qkR..vT-start (exact, no overlap with vT)
  const size_t needed = (size_t)(aB + 25165824 - (float*)d_ws) * sizeof(float);
  if (ws_size < needed) return;

  const long long qkvSBb = (long long)N_ * 3 * DIM_;   // bf16 elems per b
  const long long corrSB = (long long)H_ * N_ * N_;
  const long long corrSH = (long long)N_ * N_;
  const long long aSB = (long long)H_ * S_ * S_;
  const long long aSH = (long long)S_ * S_;
  const long long fSB = (long long)H_ * S_ * T_;
  const long long fSH = (long long)S_ * T_;
  const long long qkSB = (long long)H_ * S_ * 128;
  const long long qkSH = (long long)S_ * 128;
  const long long stSB = (long long)H_ * 64 * 256;
  const long long stSH = (long long)64 * 256;
  const long long vSB = (long long)H_ * 64 * 320;
  const long long vSH = (long long)64 * 320;

  // ---- weights -> bf16 ----
  cvt_bf16<<<(3 * DIM_ * DIM_ + 255) / 256, 256, 0, stream>>>(qkvw, wqkv, 3 * DIM_ * DIM_);
  cvt_bf16<<<(DIM_ * DIM_ + 255) / 256, 256, 0, stream>>>(projw, wproj, DIM_ * DIM_);
  cvt_bf16<<<(MLP_ * DIM_ + 255) / 256, 256, 0, stream>>>(fc1w, wfc1, MLP_ * DIM_);
  cvt_bf16<<<(MLP_ * DIM_ + 255) / 256, 256, 0, stream>>>(fc2w, wfc2, MLP_ * DIM_);
  cvt_stk<<<160, 256, 0, stream>>>(stqw, stqb, stkw, stkb, wstk, bstk);

  // ---- Phase A: LN1 + QKV (MFMA, bf16 out) + corr QK^T (batched MFMA) ----
  for (int mo = 0; mo < 2; ++mo) {
    const float* x = mo ? x_tir : x_rgb;
    __hip_bfloat16* qkvb = mo ? qkvTb : qkvRb;
    float* corr = mo ? corrT : corrR;
    ln_kernel<<<B_ * N_, 256, 0, stream>>>(x, n1w, n1b, tmpb);
    gemm_mfma<0, false, false, true><<<dim3((3 * DIM_) / 128, (B_ * N_) / 128), 256, 0, stream>>>(
        tmpb, wqkv, nullptr, nullptr, nullptr, qkvb, B_ * N_, 3 * DIM_, DIM_);
    bmm_mfma<false, false, true><<<dim3(N_ / 64, N_ / 64, B_ * H_), 256, 0, stream>>>(
        qkvb, qkvSBb, 64, 3 * DIM_,
        qkvb + DIM_, qkvSBb, 64, 3 * DIM_,
        corr, nullptr, corrSB, corrSH, N_,
        H_, 64, 0.125f, mask, N_);
  }

  // ---- Phase B: fused st q|k (MFMA), a (MFMA), f (MFMA) ----
  stqk_mfma<<<(B_ * H_ * S_) / 128, 256, 0, stream>>>(corrR, pos, wstk, bstk, qkR);
  stqk_mfma<<<(B_ * H_ * S_) / 128, 256, 0, stream>>>(corrT, pos, wstk, bstk, qkT);

  // a_rt = softmax(q_r @ k_t^T * msc); f_r = a_rt @ st_t[..., :T]
  bmm_mfma<false, false, false><<<dim3(S_ / 64, S_ / 64, B_ * H_), 256, 0, stream>>>(
      qkR, qkSB, qkSH, 128,
      qkT + 64, qkSB, qkSH, 128,
      aB, nullptr, aSB, aSH, S_,
      H_, 64, 0.125f, nullptr, 0);
  softmax256<<<B_ * H_ * S_, 256, 0, stream>>>(aB);
  transT_kernel<<<dim3(4, B_ * H_), 256, 0, stream>>>(corrT, stT);
  bmm_mfma<true, false, false><<<dim3(1, S_ / 64, B_ * H_), 256, 0, stream>>>(
      aB, aSB, aSH, S_,
      stT, stSB, stSH, 256,
      fR, nullptr, fSB, fSH, T_,
      H_, 256, 1.0f, nullptr, 0);

  // a_tr = softmax(q_t @ k_r^T * msc); f_t = a_tr @ st_r[..., :T]
  bmm_mfma<false, false, false><<<dim3(S_ / 64, S_ / 64, B_ * H_), 256, 0, stream>>>(
      qkT, qkSB, qkSH, 128,
      qkR + 64, qkSB, qkSH, 128,
      aB, nullptr, aSB, aSH, S_,
      H_, 64, 0.125f, nullptr, 0);
  softmax256<<<B_ * H_ * S_, 256, 0, stream>>>(aB);
  transT_kernel<<<dim3(4, B_ * H_), 256, 0, stream>>>(corrR, stT);
  bmm_mfma<true, false, false><<<dim3(1, S_ / 64, B_ * H_), 256, 0, stream>>>(
      aB, aSB, aSH, S_,
      stT, stSB, stSH, 256,
      fT, nullptr, fSB, fSH, T_,
      H_, 256, 1.0f, nullptr, 0);

  // ---- fused f-add + corr softmax (in place in d_out) ----
  softmax_corr<<<B_ * H_ * N_, 320, 0, stream>>>(corrR, fR);
  softmax_corr<<<B_ * H_ * N_, 320, 0, stream>>>(corrT, fT);

  // ---- Phase C: block_out per modality ----
  for (int mo = 0; mo < 2; ++mo) {
    const float* x = mo ? x_tir : x_rgb;
    const __hip_bfloat16* qkvb = mo ? qkvTb : qkvRb;
    const float* corr = mo ? corrT : corrR;
    float* outX = mo ? outT : outR;
    // vT = v^T (bf16) ; o = attn @ v -> tmpb (bf16, [b][n][h*64+j])
    transV_kernel<<<dim3(5, B_ * H_), 256, 0, stream>>>(qkvb, vT);
    bmm_mfma<true, true, false><<<dim3(1, N_ / 64, B_ * H_), 256, 0, stream>>>(
        corr, corrSB, corrSH, N_,
        vT, vSB, vSH, 320,
        nullptr, tmpb, (long long)N_ * DIM_, 64, DIM_,
        H_, 320, 1.0f, nullptr, 0);
    // x2 = x + o @ proj_w^T + proj_b -> outX
    gemm_mfma<0, true, true, false><<<dim3(DIM_ / 128, (B_ * N_) / 128), 256, 0, stream>>>(
        tmpb, wproj, projb, x, outX, nullptr, B_ * N_, DIM_, DIM_);
    // xn2 = LN2(x2) -> tmpb
    ln_kernel<<<B_ * N_, 256, 0, stream>>>(outX, n2w, n2b, tmpb);
    // h = gelu(xn2 @ fc1^T + b1) -> hb (bf16)
    gemm_mfma<1, true, false, true><<<dim3(MLP_ / 128, (B_ * N_) / 128), 256, 0, stream>>>(
        tmpb, wfc1, fc1b, nullptr, nullptr, hb, B_ * N_, MLP_, DIM_);
    // out = x2 + h @ fc2^T + b2 (in place on outX)
    gemm_mfma<0, true, true, false><<<dim3(DIM_ / 128, (B_ * N_) / 128), 256, 0, stream>>>(
        hb, wfc2, fc2b, outX, outX, nullptr, B_ * N_, DIM_, MLP_);
  }
}